// Round 2
// baseline (3352.003 us; speedup 1.0000x reference)
//
#include <hip/hip_runtime.h>
#include <math.h>

// ---------------------------------------------------------------------------
// SpatialGCN restructured:
//  * dst-sorted CSR built once per launch (hist -> scan -> scatter) so the
//    3 conv layers are node-centric GATHER kernels with zero fp atomics.
//  * per-node kernel: 4 waves/block split the 16 hidden h-rows (4 each) over
//    the same 64 nodes; partials reduced via LDS. Weights stay wave-uniform
//    (readfirstlane'd h0) -> s_load scalar path.
//  * self-loops (rel==0) folded into per-node epilogue via Wself.
// ---------------------------------------------------------------------------

struct WPtrs {
    const float* bin0; const float* wout0;
    const float* bin1; const float* wout1;
    const float* bin2; const float* wout2;
};

// Extract packed pos (N x 2) and feat (N x 16) from x (N x 18).
__global__ __launch_bounds__(256) void prep_kernel(
    const float* __restrict__ x, float* __restrict__ pos,
    float* __restrict__ feat, int n)
{
    int i = blockIdx.x * 256 + threadIdx.x;
    if (i >= n) return;
    const float* r = x + (size_t)i * 18;
    float2 p; p.x = r[0]; p.y = r[1];
    ((float2*)pos)[i] = p;
    float4* fp = (float4*)feat + (size_t)i * 4;
    fp[0] = make_float4(r[2],  r[3],  r[4],  r[5]);
    fp[1] = make_float4(r[6],  r[7],  r[8],  r[9]);
    fp[2] = make_float4(r[10], r[11], r[12], r[13]);
    fp[3] = make_float4(r[14], r[15], r[16], r[17]);
}

__global__ __launch_bounds__(256) void zero_kernel(int* __restrict__ p, int n)
{
    int i = blockIdx.x * 256 + threadIdx.x;
    if (i < n) p[i] = 0;
}

__global__ __launch_bounds__(256) void hist_kernel(
    const int* __restrict__ ei, int* __restrict__ counts, int E)
{
    int e = blockIdx.x * 256 + threadIdx.x;
    if (e < E) atomicAdd(&counts[ei[E + e]], 1);
}

// Single-workgroup exclusive scan over counts[n] -> offsets[n+1], cursor[n].
__global__ __launch_bounds__(1024) void scan_kernel(
    const int* __restrict__ counts, int* __restrict__ offsets,
    int* __restrict__ cursor, int n)
{
    __shared__ int part[1024];
    int t = threadIdx.x;
    int chunk = (n + 1023) / 1024;
    int b = t * chunk;
    int e = min(b + chunk, n);
    int s = 0;
    for (int i = b; i < e; ++i) s += counts[i];
    part[t] = s;
    __syncthreads();
    for (int off = 1; off < 1024; off <<= 1) {
        int v = (t >= off) ? part[t - off] : 0;
        __syncthreads();
        part[t] += v;
        __syncthreads();
    }
    int run = (t == 0) ? 0 : part[t - 1];
    for (int i = b; i < e; ++i) {
        offsets[i] = run;
        cursor[i]  = run;
        run += counts[i];
    }
    if (t == 1023) offsets[n] = part[1023];
}

// Scatter edges into dst-sorted order; precompute rel per sorted edge.
__global__ __launch_bounds__(256) void scatter_kernel(
    const int* __restrict__ ei, const float* __restrict__ pos,
    int* __restrict__ cursor, int* __restrict__ ssrc,
    float2* __restrict__ srel, int E)
{
    int e = blockIdx.x * 256 + threadIdx.x;
    if (e >= E) return;
    int s = ei[e];
    int d = ei[E + e];
    int p = atomicAdd(&cursor[d], 1);
    ssrc[p] = s;
    float2 ps = ((const float2*)pos)[s];
    float2 pd = ((const float2*)pos)[d];
    srel[p] = make_float2(ps.x - pd.x, ps.y - pd.y);
}

// Wself[l][c*16+o] = sum_h relu(bin[h*16+c]) * Wout[(h*16+c)*16+o]
__global__ __launch_bounds__(256) void wself_kernel(WPtrs wp, float* __restrict__ wself)
{
    int l = blockIdx.x;
    const float* bin  = (l == 0) ? wp.bin0  : (l == 1) ? wp.bin1  : wp.bin2;
    const float* wout = (l == 0) ? wp.wout0 : (l == 1) ? wp.wout1 : wp.wout2;
    int t = threadIdx.x;          // t = c*16 + o
    int c = t >> 4, o = t & 15;
    float acc = 0.f;
    #pragma unroll
    for (int h = 0; h < 16; ++h) {
        int hc = h * 16 + c;
        acc += fmaxf(bin[hc], 0.f) * wout[hc * 16 + o];
    }
    wself[l * 256 + t] = acc;
}

// Node-centric conv layer. Block = 256 threads = 4 waves over the SAME 64
// nodes; wave w computes h-rows [4w, 4w+4). Partials reduced via LDS.
__global__ __launch_bounds__(256) void node_kernel(
    const int* __restrict__ offsets, const int* __restrict__ ssrc,
    const float2* __restrict__ srel, const float* __restrict__ fin,
    const float* __restrict__ Win,  // [2,256]
    const float* __restrict__ bin,  // [256]
    const float* __restrict__ Wout, // [256,16]
    const float* __restrict__ wself,// [256]
    const float* __restrict__ bout, // [16]
    float* __restrict__ out, int n)
{
    __shared__ float part[4][64][17];   // +1 pad: conflict-free stores
    int lane = threadIdx.x & 63;
    int wv   = threadIdx.x >> 6;                       // 0..3, wave-uniform
    int h0   = __builtin_amdgcn_readfirstlane(wv * 4); // force SGPR
    int node = blockIdx.x * 64 + lane;
    bool valid = node < n;
    int i = valid ? node : 0;

    int b = offsets[i];
    int e = offsets[i + 1];
    if (!valid) e = b;

    float acc[16];
    #pragma unroll
    for (int o = 0; o < 16; ++o) acc[o] = 0.f;

    for (int k = b; k < e; ++k) {
        int s = ssrc[k];
        float2 r = srel[k];
        const float4* fp = (const float4*)fin + (size_t)s * 4;
        float4 a4 = fp[0], b4 = fp[1], c4 = fp[2], d4 = fp[3];
        float xj[16] = { a4.x,a4.y,a4.z,a4.w, b4.x,b4.y,b4.z,b4.w,
                         c4.x,c4.y,c4.z,c4.w, d4.x,d4.y,d4.z,d4.w };
        #pragma unroll
        for (int hh = 0; hh < 4; ++hh) {
            int h = h0 + hh;       // uniform
            #pragma unroll
            for (int c = 0; c < 16; ++c) {
                int hc = h * 16 + c;
                float sv = fmaf(r.x, Win[hc], fmaf(r.y, Win[256 + hc], bin[hc]));
                sv = fmaxf(sv, 0.f);
                float t = sv * xj[c];
                #pragma unroll
                for (int o = 0; o < 16; ++o)
                    acc[o] = fmaf(t, Wout[hc * 16 + o], acc[o]);
            }
        }
    }

    // fold self-loop + bias into wave 0's partial
    if (wv == 0 && valid) {
        const float4* ip = (const float4*)fin + (size_t)i * 4;
        float4 a4 = ip[0], b4 = ip[1], c4 = ip[2], d4 = ip[3];
        float xin[16] = { a4.x,a4.y,a4.z,a4.w, b4.x,b4.y,b4.z,b4.w,
                          c4.x,c4.y,c4.z,c4.w, d4.x,d4.y,d4.z,d4.w };
        #pragma unroll
        for (int o = 0; o < 16; ++o) acc[o] += bout[o];
        #pragma unroll
        for (int c = 0; c < 16; ++c) {
            float t = xin[c];
            #pragma unroll
            for (int o = 0; o < 16; ++o)
                acc[o] = fmaf(t, wself[c * 16 + o], acc[o]);
        }
    }

    #pragma unroll
    for (int o = 0; o < 16; ++o) part[wv][lane][o] = acc[o];
    __syncthreads();

    // reduce: 256 threads = 64 nodes x 4 output-quads
    int l2 = threadIdx.x >> 2;
    int oq = (threadIdx.x & 3) * 4;
    int node2 = blockIdx.x * 64 + l2;
    if (node2 < n) {
        float4 v;
        v.x = part[0][l2][oq+0] + part[1][l2][oq+0] + part[2][l2][oq+0] + part[3][l2][oq+0];
        v.y = part[0][l2][oq+1] + part[1][l2][oq+1] + part[2][l2][oq+1] + part[3][l2][oq+1];
        v.z = part[0][l2][oq+2] + part[1][l2][oq+2] + part[2][l2][oq+2] + part[3][l2][oq+2];
        v.w = part[0][l2][oq+3] + part[1][l2][oq+3] + part[2][l2][oq+3] + part[3][l2][oq+3];
        ((float4*)(out + (size_t)node2 * 16))[threadIdx.x & 3] = v;
    }
}

// Edge MLP: sigmoid(relu(relu([h_s,h_d]@Wd1+b1)@Wd2+b2)@Wd3+b3)
__global__ __launch_bounds__(256) void decode_kernel(
    const int* __restrict__ ei, const float* __restrict__ h,
    const float* __restrict__ Wd1, const float* __restrict__ bd1,
    const float* __restrict__ Wd2, const float* __restrict__ bd2,
    const float* __restrict__ Wd3, const float* __restrict__ bd3,
    float* __restrict__ out, int E)
{
    int tid = blockIdx.x * 256 + threadIdx.x;
    bool valid = (tid < E);
    int e = valid ? tid : 0;
    int s = ei[e];
    int d = ei[E + e];

    const float4* hp = (const float4*)h + (size_t)s * 4;
    float4 a = hp[0], b = hp[1], c4 = hp[2], d4 = hp[3];
    float hs[16] = { a.x,a.y,a.z,a.w, b.x,b.y,b.z,b.w,
                     c4.x,c4.y,c4.z,c4.w, d4.x,d4.y,d4.z,d4.w };
    const float4* hq = (const float4*)h + (size_t)d * 4;
    float4 e0 = hq[0], e1 = hq[1], e2 = hq[2], e3 = hq[3];
    float hd[16] = { e0.x,e0.y,e0.z,e0.w, e1.x,e1.y,e1.z,e1.w,
                     e2.x,e2.y,e2.z,e2.w, e3.x,e3.y,e3.z,e3.w };

    float z1[16];
    #pragma unroll
    for (int o = 0; o < 16; ++o) z1[o] = bd1[o];
    #pragma unroll
    for (int c = 0; c < 16; ++c) {
        float u = hs[c], v = hd[c];
        #pragma unroll
        for (int o = 0; o < 16; ++o)
            z1[o] = fmaf(u, Wd1[c * 16 + o], fmaf(v, Wd1[(16 + c) * 16 + o], z1[o]));
    }

    float z2[16];
    #pragma unroll
    for (int o = 0; o < 16; ++o) z2[o] = bd2[o];
    #pragma unroll
    for (int c = 0; c < 16; ++c) {
        float t = fmaxf(z1[c], 0.f);
        #pragma unroll
        for (int o = 0; o < 16; ++o)
            z2[o] = fmaf(t, Wd2[c * 16 + o], z2[o]);
    }

    float y = bd3[0];
    #pragma unroll
    for (int c = 0; c < 16; ++c)
        y = fmaf(fmaxf(z2[c], 0.f), Wd3[c], y);

    if (valid)
        out[tid] = 1.f / (1.f + expf(-y));
}

extern "C" void kernel_launch(void* const* d_in, const int* in_sizes, int n_in,
                              void* d_out, int out_size, void* d_ws, size_t ws_size,
                              hipStream_t stream)
{
    const float* x     = (const float*)d_in[0];
    const int*   ei    = (const int*)  d_in[1];
    const float* Win1  = (const float*)d_in[2];
    const float* bin1  = (const float*)d_in[3];
    const float* Wout1 = (const float*)d_in[4];
    const float* bout1 = (const float*)d_in[5];
    const float* Win2  = (const float*)d_in[6];
    const float* bin2  = (const float*)d_in[7];
    const float* Wout2 = (const float*)d_in[8];
    const float* bout2 = (const float*)d_in[9];
    const float* Win3  = (const float*)d_in[10];
    const float* bin3  = (const float*)d_in[11];
    const float* Wout3 = (const float*)d_in[12];
    const float* bout3 = (const float*)d_in[13];
    const float* Wd1   = (const float*)d_in[14];
    const float* bd1   = (const float*)d_in[15];
    const float* Wd2   = (const float*)d_in[16];
    const float* bd2   = (const float*)d_in[17];
    const float* Wd3   = (const float*)d_in[18];
    const float* bd3   = (const float*)d_in[19];

    int n = in_sizes[0] / 18;
    int E = in_sizes[1] / 2;

    float* ws    = (float*)d_ws;
    float* pos   = ws;                        // 2n
    float* feat  = pos   + (size_t)2 * n;     // 16n
    float* hA    = feat  + (size_t)16 * n;    // 16n
    float* hB    = hA    + (size_t)16 * n;    // 16n
    float* wself = hB    + (size_t)16 * n;    // 768
    int* counts  = (int*)(wself + 768);       // n
    int* offsets = counts + n;                // n+1 (+1 pad for 8B align of srel)
    int* cursor  = offsets + n + 2;           // n
    int* ssrc    = cursor + n;                // E
    float2* srel = (float2*)(ssrc + E);       // E (8B aligned by construction)
    float* outp  = (float*)d_out;

    int nb_n  = (n + 255) / 256;
    int nb_e  = (E + 255) / 256;
    int nb_nk = (n + 63) / 64;

    prep_kernel<<<nb_n, 256, 0, stream>>>(x, pos, feat, n);
    zero_kernel<<<nb_n, 256, 0, stream>>>(counts, n);
    hist_kernel<<<nb_e, 256, 0, stream>>>(ei, counts, E);
    scan_kernel<<<1, 1024, 0, stream>>>(counts, offsets, cursor, n);
    scatter_kernel<<<nb_e, 256, 0, stream>>>(ei, pos, cursor, ssrc, srel, E);

    WPtrs wp { bin1, Wout1, bin2, Wout2, bin3, Wout3 };
    wself_kernel<<<3, 256, 0, stream>>>(wp, wself);

    node_kernel<<<nb_nk, 256, 0, stream>>>(offsets, ssrc, srel, feat,
                                           Win1, bin1, Wout1, wself + 0,   bout1, hA, n);
    node_kernel<<<nb_nk, 256, 0, stream>>>(offsets, ssrc, srel, hA,
                                           Win2, bin2, Wout2, wself + 256, bout2, hB, n);
    node_kernel<<<nb_nk, 256, 0, stream>>>(offsets, ssrc, srel, hB,
                                           Win3, bin3, Wout3, wself + 512, bout3, hA, n);

    decode_kernel<<<nb_e, 256, 0, stream>>>(ei, hA, Wd1, bd1, Wd2, bd2, Wd3, bd3,
                                            outp, E);
}

// Round 3
// 474.623 us; speedup vs baseline: 7.0624x; 7.0624x over previous
//
#include <hip/hip_runtime.h>
#include <math.h>

// ---------------------------------------------------------------------------
// SpatialGCN:
//  * CSR (dst-sorted) built once: hist -> scan -> scatter.
//  * Per layer: edge-parallel contribution kernel (plain stores into sorted
//    slots, NO atomics) + node segmented-sum kernel (4 threads/node).
//  * Self-loops + bias folded into segsum via Wself.
// ---------------------------------------------------------------------------

struct WPtrs {
    const float* bin0; const float* wout0;
    const float* bin1; const float* wout1;
    const float* bin2; const float* wout2;
};

// Extract packed pos (N x 2) and feat (N x 16) from x (N x 18).
__global__ __launch_bounds__(256) void prep_kernel(
    const float* __restrict__ x, float* __restrict__ pos,
    float* __restrict__ feat, int n)
{
    int i = blockIdx.x * 256 + threadIdx.x;
    if (i >= n) return;
    const float* r = x + (size_t)i * 18;
    float2 p; p.x = r[0]; p.y = r[1];
    ((float2*)pos)[i] = p;
    float4* fp = (float4*)feat + (size_t)i * 4;
    fp[0] = make_float4(r[2],  r[3],  r[4],  r[5]);
    fp[1] = make_float4(r[6],  r[7],  r[8],  r[9]);
    fp[2] = make_float4(r[10], r[11], r[12], r[13]);
    fp[3] = make_float4(r[14], r[15], r[16], r[17]);
}

__global__ __launch_bounds__(256) void zero_kernel(int* __restrict__ p, int n)
{
    int i = blockIdx.x * 256 + threadIdx.x;
    if (i < n) p[i] = 0;
}

__global__ __launch_bounds__(256) void hist_kernel(
    const int* __restrict__ ei, int* __restrict__ counts, int E)
{
    int e = blockIdx.x * 256 + threadIdx.x;
    if (e < E) atomicAdd(&counts[ei[E + e]], 1);
}

// Single-workgroup exclusive scan over counts[n] -> offsets[n+1], cursor[n].
__global__ __launch_bounds__(1024) void scan_kernel(
    const int* __restrict__ counts, int* __restrict__ offsets,
    int* __restrict__ cursor, int n)
{
    __shared__ int part[1024];
    int t = threadIdx.x;
    int chunk = (n + 1023) / 1024;
    int b = t * chunk;
    int e = min(b + chunk, n);
    int s = 0;
    for (int i = b; i < e; ++i) s += counts[i];
    part[t] = s;
    __syncthreads();
    for (int off = 1; off < 1024; off <<= 1) {
        int v = (t >= off) ? part[t - off] : 0;
        __syncthreads();
        part[t] += v;
        __syncthreads();
    }
    int run = (t == 0) ? 0 : part[t - 1];
    for (int i = b; i < e; ++i) {
        offsets[i] = run;
        cursor[i]  = run;
        run += counts[i];
    }
    if (t == 1023) offsets[n] = part[1023];
}

// Scatter edges into dst-sorted order; precompute rel per sorted edge.
__global__ __launch_bounds__(256) void scatter_kernel(
    const int* __restrict__ ei, const float* __restrict__ pos,
    int* __restrict__ cursor, int* __restrict__ ssrc,
    float2* __restrict__ srel, int E)
{
    int e = blockIdx.x * 256 + threadIdx.x;
    if (e >= E) return;
    int s = ei[e];
    int d = ei[E + e];
    int p = atomicAdd(&cursor[d], 1);
    ssrc[p] = s;
    float2 ps = ((const float2*)pos)[s];
    float2 pd = ((const float2*)pos)[d];
    srel[p] = make_float2(ps.x - pd.x, ps.y - pd.y);
}

// Wself[l][c*16+o] = sum_h relu(bin[h*16+c]) * Wout[(h*16+c)*16+o]
__global__ __launch_bounds__(256) void wself_kernel(WPtrs wp, float* __restrict__ wself)
{
    int l = blockIdx.x;
    const float* bin  = (l == 0) ? wp.bin0  : (l == 1) ? wp.bin1  : wp.bin2;
    const float* wout = (l == 0) ? wp.wout0 : (l == 1) ? wp.wout1 : wp.wout2;
    int t = threadIdx.x;          // t = c*16 + o
    int c = t >> 4, o = t & 15;
    float acc = 0.f;
    #pragma unroll
    for (int h = 0; h < 16; ++h) {
        int hc = h * 16 + c;
        acc += fmaxf(bin[hc], 0.f) * wout[hc * 16 + o];
    }
    wself[l * 256 + t] = acc;
}

// One thread per sorted edge slot: contribution = (relu(rel@Win+bin)*xj)@Wout,
// written to contrib[p][0..16) with plain stores (slot owned exclusively).
__global__ __launch_bounds__(256) void edge_contrib_kernel(
    const int* __restrict__ ssrc,   // [E] sorted src
    const float2* __restrict__ srel,// [E] sorted rel
    const float* __restrict__ fin,  // [N,16]
    const float* __restrict__ Win,  // [2,256]
    const float* __restrict__ bin,  // [256]
    const float* __restrict__ Wout, // [256,16]
    float* __restrict__ contrib,    // [E,16]
    int E)
{
    int p = blockIdx.x * 256 + threadIdx.x;
    bool valid = (p < E);
    int pp = valid ? p : 0;
    int s = ssrc[pp];
    float2 r = srel[pp];

    const float4* fp = (const float4*)fin + (size_t)s * 4;
    float4 a = fp[0], b = fp[1], c4 = fp[2], d4 = fp[3];
    float xj[16] = { a.x,a.y,a.z,a.w, b.x,b.y,b.z,b.w,
                     c4.x,c4.y,c4.z,c4.w, d4.x,d4.y,d4.z,d4.w };

    float acc[16];
    #pragma unroll
    for (int o = 0; o < 16; ++o) acc[o] = 0.f;

    // weights are wave-uniform -> scalar loads; unroll 1 keeps SGPR live-range small
    #pragma unroll 1
    for (int h = 0; h < 16; ++h) {
        #pragma unroll
        for (int c = 0; c < 16; ++c) {
            int hc = h * 16 + c;
            float sv = fmaf(r.x, Win[hc], fmaf(r.y, Win[256 + hc], bin[hc]));
            sv = fmaxf(sv, 0.f);
            float t = sv * xj[c];
            const float* wr = Wout + hc * 16;
            #pragma unroll
            for (int o = 0; o < 16; ++o)
                acc[o] = fmaf(t, wr[o], acc[o]);
        }
    }

    if (valid) {
        float4* op = (float4*)(contrib + (size_t)p * 16);
        op[0] = make_float4(acc[0],  acc[1],  acc[2],  acc[3]);
        op[1] = make_float4(acc[4],  acc[5],  acc[6],  acc[7]);
        op[2] = make_float4(acc[8],  acc[9],  acc[10], acc[11]);
        op[3] = make_float4(acc[12], acc[13], acc[14], acc[15]);
    }
}

// 4 threads per node, one float4 channel-quad each. Init = bias + self-loop
// (fin[node] @ Wself), then sum sorted contributions over the CSR range.
__global__ __launch_bounds__(256) void segsum_kernel(
    const int* __restrict__ offsets, const float* __restrict__ contrib,
    const float* __restrict__ fin, const float* __restrict__ wself,
    const float* __restrict__ bout, float* __restrict__ out, int n)
{
    int tid = blockIdx.x * 256 + threadIdx.x;
    int node = tid >> 2;
    int q = tid & 3;            // channel quad index
    if (node >= n) return;

    const float4* ip = (const float4*)fin + (size_t)node * 4;
    float4 f0 = ip[0], f1 = ip[1], f2 = ip[2], f3 = ip[3];
    float xin[16] = { f0.x,f0.y,f0.z,f0.w, f1.x,f1.y,f1.z,f1.w,
                      f2.x,f2.y,f2.z,f2.w, f3.x,f3.y,f3.z,f3.w };

    float4 acc = ((const float4*)bout)[q];
    #pragma unroll
    for (int c = 0; c < 16; ++c) {
        float t = xin[c];
        float4 w = ((const float4*)wself)[c * 4 + q];
        acc.x = fmaf(t, w.x, acc.x);
        acc.y = fmaf(t, w.y, acc.y);
        acc.z = fmaf(t, w.z, acc.z);
        acc.w = fmaf(t, w.w, acc.w);
    }

    int b = offsets[node];
    int e = offsets[node + 1];
    for (int k = b; k < e; ++k) {
        float4 v = ((const float4*)contrib)[(size_t)k * 4 + q];
        acc.x += v.x; acc.y += v.y; acc.z += v.z; acc.w += v.w;
    }

    ((float4*)(out + (size_t)node * 16))[q] = acc;
}

// Edge MLP: sigmoid(relu(relu([h_s,h_d]@Wd1+b1)@Wd2+b2)@Wd3+b3)
__global__ __launch_bounds__(256) void decode_kernel(
    const int* __restrict__ ei, const float* __restrict__ h,
    const float* __restrict__ Wd1, const float* __restrict__ bd1,
    const float* __restrict__ Wd2, const float* __restrict__ bd2,
    const float* __restrict__ Wd3, const float* __restrict__ bd3,
    float* __restrict__ out, int E)
{
    int tid = blockIdx.x * 256 + threadIdx.x;
    bool valid = (tid < E);
    int e = valid ? tid : 0;
    int s = ei[e];
    int d = ei[E + e];

    const float4* hp = (const float4*)h + (size_t)s * 4;
    float4 a = hp[0], b = hp[1], c4 = hp[2], d4 = hp[3];
    float hs[16] = { a.x,a.y,a.z,a.w, b.x,b.y,b.z,b.w,
                     c4.x,c4.y,c4.z,c4.w, d4.x,d4.y,d4.z,d4.w };
    const float4* hq = (const float4*)h + (size_t)d * 4;
    float4 e0 = hq[0], e1 = hq[1], e2 = hq[2], e3 = hq[3];
    float hd[16] = { e0.x,e0.y,e0.z,e0.w, e1.x,e1.y,e1.z,e1.w,
                     e2.x,e2.y,e2.z,e2.w, e3.x,e3.y,e3.z,e3.w };

    float z1[16];
    #pragma unroll
    for (int o = 0; o < 16; ++o) z1[o] = bd1[o];
    #pragma unroll
    for (int c = 0; c < 16; ++c) {
        float u = hs[c], v = hd[c];
        #pragma unroll
        for (int o = 0; o < 16; ++o)
            z1[o] = fmaf(u, Wd1[c * 16 + o], fmaf(v, Wd1[(16 + c) * 16 + o], z1[o]));
    }

    float z2[16];
    #pragma unroll
    for (int o = 0; o < 16; ++o) z2[o] = bd2[o];
    #pragma unroll
    for (int c = 0; c < 16; ++c) {
        float t = fmaxf(z1[c], 0.f);
        #pragma unroll
        for (int o = 0; o < 16; ++o)
            z2[o] = fmaf(t, Wd2[c * 16 + o], z2[o]);
    }

    float y = bd3[0];
    #pragma unroll
    for (int c = 0; c < 16; ++c)
        y = fmaf(fmaxf(z2[c], 0.f), Wd3[c], y);

    if (valid)
        out[tid] = 1.f / (1.f + expf(-y));
}

extern "C" void kernel_launch(void* const* d_in, const int* in_sizes, int n_in,
                              void* d_out, int out_size, void* d_ws, size_t ws_size,
                              hipStream_t stream)
{
    const float* x     = (const float*)d_in[0];
    const int*   ei    = (const int*)  d_in[1];
    const float* Win1  = (const float*)d_in[2];
    const float* bin1  = (const float*)d_in[3];
    const float* Wout1 = (const float*)d_in[4];
    const float* bout1 = (const float*)d_in[5];
    const float* Win2  = (const float*)d_in[6];
    const float* bin2  = (const float*)d_in[7];
    const float* Wout2 = (const float*)d_in[8];
    const float* bout2 = (const float*)d_in[9];
    const float* Win3  = (const float*)d_in[10];
    const float* bin3  = (const float*)d_in[11];
    const float* Wout3 = (const float*)d_in[12];
    const float* bout3 = (const float*)d_in[13];
    const float* Wd1   = (const float*)d_in[14];
    const float* bd1   = (const float*)d_in[15];
    const float* Wd2   = (const float*)d_in[16];
    const float* bd2   = (const float*)d_in[17];
    const float* Wd3   = (const float*)d_in[18];
    const float* bd3   = (const float*)d_in[19];

    int n = in_sizes[0] / 18;
    int E = in_sizes[1] / 2;

    float* ws      = (float*)d_ws;
    float* pos     = ws;                        // 2n
    float* feat    = pos   + (size_t)2 * n;     // 16n
    float* hA      = feat  + (size_t)16 * n;    // 16n
    float* hB      = hA    + (size_t)16 * n;    // 16n
    float* wself   = hB    + (size_t)16 * n;    // 768
    int* counts    = (int*)(wself + 768);       // n
    int* offsets   = counts + n;                // n+1
    int* cursor    = offsets + n + 2;           // n
    int* ssrc      = cursor + n;                // E
    float2* srel   = (float2*)(ssrc + E);       // E (8B aligned)
    float* contrib = (float*)(srel + E);        // 16E (32 MB, reused per layer)
    float* outp    = (float*)d_out;

    int nb_n  = (n + 255) / 256;
    int nb_e  = (E + 255) / 256;
    int nb_s  = (4 * n + 255) / 256;

    prep_kernel<<<nb_n, 256, 0, stream>>>(x, pos, feat, n);
    zero_kernel<<<nb_n, 256, 0, stream>>>(counts, n);
    hist_kernel<<<nb_e, 256, 0, stream>>>(ei, counts, E);
    scan_kernel<<<1, 1024, 0, stream>>>(counts, offsets, cursor, n);
    scatter_kernel<<<nb_e, 256, 0, stream>>>(ei, pos, cursor, ssrc, srel, E);

    WPtrs wp { bin1, Wout1, bin2, Wout2, bin3, Wout3 };
    wself_kernel<<<3, 256, 0, stream>>>(wp, wself);

    // Layer 1: feat -> hA
    edge_contrib_kernel<<<nb_e, 256, 0, stream>>>(ssrc, srel, feat, Win1, bin1, Wout1, contrib, E);
    segsum_kernel<<<nb_s, 256, 0, stream>>>(offsets, contrib, feat, wself + 0,   bout1, hA, n);
    // Layer 2: hA -> hB
    edge_contrib_kernel<<<nb_e, 256, 0, stream>>>(ssrc, srel, hA,   Win2, bin2, Wout2, contrib, E);
    segsum_kernel<<<nb_s, 256, 0, stream>>>(offsets, contrib, hA,   wself + 256, bout2, hB, n);
    // Layer 3: hB -> hA
    edge_contrib_kernel<<<nb_e, 256, 0, stream>>>(ssrc, srel, hB,   Win3, bin3, Wout3, contrib, E);
    segsum_kernel<<<nb_s, 256, 0, stream>>>(offsets, contrib, hB,   wself + 512, bout3, hA, n);

    decode_kernel<<<nb_e, 256, 0, stream>>>(ei, hA, Wd1, bd1, Wd2, bd2, Wd3, bd3,
                                            outp, E);
}

// Round 5
// 370.448 us; speedup vs baseline: 9.0485x; 1.2812x over previous
//
#include <hip/hip_runtime.h>
#include <math.h>

// ---------------------------------------------------------------------------
// SpatialGCN:
//  * CSR (dst-grouped, UNORDERED groups) built via hist -> block-scan
//    reservation (196 global atomics) -> scatter. No serial device scan.
//  * Per layer: edge-parallel contribution kernel (plain stores, no atomics)
//    + node segmented-sum kernel (4 threads/node).
//  * Self-loops + bias folded into segsum via Wself.
// ---------------------------------------------------------------------------

struct WPtrs {
    const float* bin0; const float* wout0;
    const float* bin1; const float* wout1;
    const float* bin2; const float* wout2;
};

// Extract packed pos (N x 2) and feat (N x 16) from x (N x 18).
__global__ __launch_bounds__(256) void prep_kernel(
    const float* __restrict__ x, float* __restrict__ pos,
    float* __restrict__ feat, int n)
{
    int i = blockIdx.x * 256 + threadIdx.x;
    if (i >= n) return;
    const float* r = x + (size_t)i * 18;
    float2 p; p.x = r[0]; p.y = r[1];
    ((float2*)pos)[i] = p;
    float4* fp = (float4*)feat + (size_t)i * 4;
    fp[0] = make_float4(r[2],  r[3],  r[4],  r[5]);
    fp[1] = make_float4(r[6],  r[7],  r[8],  r[9]);
    fp[2] = make_float4(r[10], r[11], r[12], r[13]);
    fp[3] = make_float4(r[14], r[15], r[16], r[17]);
}

// zero counts[n] and the global cursor total (ws is 0xAA-poisoned each call)
__global__ __launch_bounds__(256) void zero_kernel(int* __restrict__ p, int* __restrict__ total, int n)
{
    int i = blockIdx.x * 256 + threadIdx.x;
    if (i < n) p[i] = 0;
    if (i == 0) *total = 0;
}

__global__ __launch_bounds__(256) void hist_kernel(
    const int* __restrict__ ei, int* __restrict__ counts, int E)
{
    int e = blockIdx.x * 256 + threadIdx.x;
    if (e < E) atomicAdd(&counts[ei[E + e]], 1);
}

// Parallel slot reservation: per-block LDS inclusive scan of 256 counts,
// one global atomicAdd per block, write start/cursor. Groups end up in
// arbitrary order — segment_sum doesn't care.
__global__ __launch_bounds__(256) void reserve_kernel(
    const int* __restrict__ counts, int* __restrict__ start,
    int* __restrict__ cursor, int* __restrict__ total, int n)
{
    __shared__ int sdata[256];
    __shared__ int sbase;
    int t = threadIdx.x;
    int i = blockIdx.x * 256 + t;
    int c = (i < n) ? counts[i] : 0;
    sdata[t] = c;
    __syncthreads();
    #pragma unroll
    for (int off = 1; off < 256; off <<= 1) {
        int v = (t >= off) ? sdata[t - off] : 0;
        __syncthreads();
        sdata[t] += v;
        __syncthreads();
    }
    if (t == 255) sbase = atomicAdd(total, sdata[255]);
    __syncthreads();
    if (i < n) {
        int s = sbase + sdata[t] - c;   // block base + exclusive prefix
        start[i]  = s;
        cursor[i] = s;
    }
}

// Scatter edges into dst-grouped order; precompute rel per sorted edge.
__global__ __launch_bounds__(256) void scatter_kernel(
    const int* __restrict__ ei, const float* __restrict__ pos,
    int* __restrict__ cursor, int* __restrict__ ssrc,
    float2* __restrict__ srel, int E)
{
    int e = blockIdx.x * 256 + threadIdx.x;
    if (e >= E) return;
    int s = ei[e];
    int d = ei[E + e];
    int p = atomicAdd(&cursor[d], 1);
    ssrc[p] = s;
    float2 ps = ((const float2*)pos)[s];
    float2 pd = ((const float2*)pos)[d];
    srel[p] = make_float2(ps.x - pd.x, ps.y - pd.y);
}

// Wself[l][c*16+o] = sum_h relu(bin[h*16+c]) * Wout[(h*16+c)*16+o]
__global__ __launch_bounds__(256) void wself_kernel(WPtrs wp, float* __restrict__ wself)
{
    int l = blockIdx.x;
    const float* bin  = (l == 0) ? wp.bin0  : (l == 1) ? wp.bin1  : wp.bin2;
    const float* wout = (l == 0) ? wp.wout0 : (l == 1) ? wp.wout1 : wp.wout2;
    int t = threadIdx.x;          // t = c*16 + o
    int c = t >> 4, o = t & 15;
    float acc = 0.f;
    #pragma unroll
    for (int h = 0; h < 16; ++h) {
        int hc = h * 16 + c;
        acc += fmaxf(bin[hc], 0.f) * wout[hc * 16 + o];
    }
    wself[l * 256 + t] = acc;
}

// One thread per grouped edge slot: contribution = (relu(rel@Win+bin)*xj)@Wout,
// written to contrib[p][0..16) with plain stores (slot owned exclusively).
__global__ __launch_bounds__(256) void edge_contrib_kernel(
    const int* __restrict__ ssrc,   // [E] grouped src
    const float2* __restrict__ srel,// [E] grouped rel
    const float* __restrict__ fin,  // [N,16]
    const float* __restrict__ Win,  // [2,256]
    const float* __restrict__ bin,  // [256]
    const float* __restrict__ Wout, // [256,16]
    float* __restrict__ contrib,    // [E,16]
    int E)
{
    int p = blockIdx.x * 256 + threadIdx.x;
    bool valid = (p < E);
    int pp = valid ? p : 0;
    int s = ssrc[pp];
    float2 r = srel[pp];

    const float4* fp = (const float4*)fin + (size_t)s * 4;
    float4 a = fp[0], b = fp[1], c4 = fp[2], d4 = fp[3];
    float xj[16] = { a.x,a.y,a.z,a.w, b.x,b.y,b.z,b.w,
                     c4.x,c4.y,c4.z,c4.w, d4.x,d4.y,d4.z,d4.w };

    float acc[16];
    #pragma unroll
    for (int o = 0; o < 16; ++o) acc[o] = 0.f;

    // weights are wave-uniform -> scalar loads; unroll 1 keeps SGPR live-range small
    #pragma unroll 1
    for (int h = 0; h < 16; ++h) {
        #pragma unroll
        for (int c = 0; c < 16; ++c) {
            int hc = h * 16 + c;
            float sv = fmaf(r.x, Win[hc], fmaf(r.y, Win[256 + hc], bin[hc]));
            sv = fmaxf(sv, 0.f);
            float t = sv * xj[c];
            const float* wr = Wout + hc * 16;
            #pragma unroll
            for (int o = 0; o < 16; ++o)
                acc[o] = fmaf(t, wr[o], acc[o]);
        }
    }

    if (valid) {
        float4* op = (float4*)(contrib + (size_t)p * 16);
        op[0] = make_float4(acc[0],  acc[1],  acc[2],  acc[3]);
        op[1] = make_float4(acc[4],  acc[5],  acc[6],  acc[7]);
        op[2] = make_float4(acc[8],  acc[9],  acc[10], acc[11]);
        op[3] = make_float4(acc[12], acc[13], acc[14], acc[15]);
    }
}

// 4 threads per node, one float4 channel-quad each. Init = bias + self-loop
// (fin[node] @ Wself), then sum grouped contributions over [start, start+cnt).
__global__ __launch_bounds__(256) void segsum_kernel(
    const int* __restrict__ start, const int* __restrict__ counts,
    const float* __restrict__ contrib,
    const float* __restrict__ fin, const float* __restrict__ wself,
    const float* __restrict__ bout, float* __restrict__ out, int n)
{
    int tid = blockIdx.x * 256 + threadIdx.x;
    int node = tid >> 2;
    int q = tid & 3;            // channel quad index
    if (node >= n) return;

    const float4* ip = (const float4*)fin + (size_t)node * 4;
    float4 f0 = ip[0], f1 = ip[1], f2 = ip[2], f3 = ip[3];
    float xin[16] = { f0.x,f0.y,f0.z,f0.w, f1.x,f1.y,f1.z,f1.w,
                      f2.x,f2.y,f2.z,f2.w, f3.x,f3.y,f3.z,f3.w };

    float4 acc = ((const float4*)bout)[q];
    #pragma unroll
    for (int c = 0; c < 16; ++c) {
        float t = xin[c];
        float4 w = ((const float4*)wself)[c * 4 + q];
        acc.x = fmaf(t, w.x, acc.x);
        acc.y = fmaf(t, w.y, acc.y);
        acc.z = fmaf(t, w.z, acc.z);
        acc.w = fmaf(t, w.w, acc.w);
    }

    int b = start[node];
    int e = b + counts[node];
    for (int k = b; k < e; ++k) {
        float4 v = ((const float4*)contrib)[(size_t)k * 4 + q];
        acc.x += v.x; acc.y += v.y; acc.z += v.z; acc.w += v.w;
    }

    ((float4*)(out + (size_t)node * 16))[q] = acc;
}

// Edge MLP: sigmoid(relu(relu([h_s,h_d]@Wd1+b1)@Wd2+b2)@Wd3+b3)
__global__ __launch_bounds__(256) void decode_kernel(
    const int* __restrict__ ei, const float* __restrict__ h,
    const float* __restrict__ Wd1, const float* __restrict__ bd1,
    const float* __restrict__ Wd2, const float* __restrict__ bd2,
    const float* __restrict__ Wd3, const float* __restrict__ bd3,
    float* __restrict__ out, int E)
{
    int tid = blockIdx.x * 256 + threadIdx.x;
    bool valid = (tid < E);
    int e = valid ? tid : 0;
    int s = ei[e];
    int d = ei[E + e];

    const float4* hp = (const float4*)h + (size_t)s * 4;
    float4 a = hp[0], b = hp[1], c4 = hp[2], d4 = hp[3];
    float hs[16] = { a.x,a.y,a.z,a.w, b.x,b.y,b.z,b.w,
                     c4.x,c4.y,c4.z,c4.w, d4.x,d4.y,d4.z,d4.w };
    const float4* hq = (const float4*)h + (size_t)d * 4;
    float4 e0 = hq[0], e1 = hq[1], e2 = hq[2], e3 = hq[3];
    float hd[16] = { e0.x,e0.y,e0.z,e0.w, e1.x,e1.y,e1.z,e1.w,
                     e2.x,e2.y,e2.z,e2.w, e3.x,e3.y,e3.z,e3.w };

    float z1[16];
    #pragma unroll
    for (int o = 0; o < 16; ++o) z1[o] = bd1[o];
    #pragma unroll
    for (int c = 0; c < 16; ++c) {
        float u = hs[c], v = hd[c];
        #pragma unroll
        for (int o = 0; o < 16; ++o)
            z1[o] = fmaf(u, Wd1[c * 16 + o], fmaf(v, Wd1[(16 + c) * 16 + o], z1[o]));
    }

    float z2[16];
    #pragma unroll
    for (int o = 0; o < 16; ++o) z2[o] = bd2[o];
    #pragma unroll
    for (int c = 0; c < 16; ++c) {
        float t = fmaxf(z1[c], 0.f);
        #pragma unroll
        for (int o = 0; o < 16; ++o)
            z2[o] = fmaf(t, Wd2[c * 16 + o], z2[o]);
    }

    float y = bd3[0];
    #pragma unroll
    for (int c = 0; c < 16; ++c)
        y = fmaf(fmaxf(z2[c], 0.f), Wd3[c], y);

    if (valid)
        out[tid] = 1.f / (1.f + expf(-y));
}

extern "C" void kernel_launch(void* const* d_in, const int* in_sizes, int n_in,
                              void* d_out, int out_size, void* d_ws, size_t ws_size,
                              hipStream_t stream)
{
    const float* x     = (const float*)d_in[0];
    const int*   ei    = (const int*)  d_in[1];
    const float* Win1  = (const float*)d_in[2];
    const float* bin1  = (const float*)d_in[3];
    const float* Wout1 = (const float*)d_in[4];
    const float* bout1 = (const float*)d_in[5];
    const float* Win2  = (const float*)d_in[6];
    const float* bin2  = (const float*)d_in[7];
    const float* Wout2 = (const float*)d_in[8];
    const float* bout2 = (const float*)d_in[9];
    const float* Win3  = (const float*)d_in[10];
    const float* bin3  = (const float*)d_in[11];
    const float* Wout3 = (const float*)d_in[12];
    const float* bout3 = (const float*)d_in[13];
    const float* Wd1   = (const float*)d_in[14];
    const float* bd1   = (const float*)d_in[15];
    const float* Wd2   = (const float*)d_in[16];
    const float* bd2   = (const float*)d_in[17];
    const float* Wd3   = (const float*)d_in[18];
    const float* bd3   = (const float*)d_in[19];

    int n = in_sizes[0] / 18;
    int E = in_sizes[1] / 2;

    float* ws      = (float*)d_ws;
    float* pos     = ws;                        // 2n
    float* feat    = pos   + (size_t)2 * n;     // 16n
    float* hA      = feat  + (size_t)16 * n;    // 16n
    float* hB      = hA    + (size_t)16 * n;    // 16n
    float* wself   = hB    + (size_t)16 * n;    // 768
    int* counts    = (int*)(wself + 768);       // n
    int* start     = counts + n;                // n
    int* cursor    = start + n;                 // n
    int* total     = cursor + n;                // 1 (+1 pad -> 8B align)
    int* ssrc      = total + 2;                 // E
    float2* srel   = (float2*)(ssrc + E);       // E (8B aligned)
    float* contrib = (float*)(srel + E);        // 16E (32 MB, reused per layer)
    float* outp    = (float*)d_out;

    int nb_n  = (n + 255) / 256;
    int nb_e  = (E + 255) / 256;
    int nb_s  = (4 * n + 255) / 256;

    prep_kernel<<<nb_n, 256, 0, stream>>>(x, pos, feat, n);
    zero_kernel<<<nb_n, 256, 0, stream>>>(counts, total, n);
    hist_kernel<<<nb_e, 256, 0, stream>>>(ei, counts, E);
    reserve_kernel<<<nb_n, 256, 0, stream>>>(counts, start, cursor, total, n);
    scatter_kernel<<<nb_e, 256, 0, stream>>>(ei, pos, cursor, ssrc, srel, E);

    WPtrs wp { bin1, Wout1, bin2, Wout2, bin3, Wout3 };
    wself_kernel<<<3, 256, 0, stream>>>(wp, wself);

    // Layer 1: feat -> hA
    edge_contrib_kernel<<<nb_e, 256, 0, stream>>>(ssrc, srel, feat, Win1, bin1, Wout1, contrib, E);
    segsum_kernel<<<nb_s, 256, 0, stream>>>(start, counts, contrib, feat, wself + 0,   bout1, hA, n);
    // Layer 2: hA -> hB
    edge_contrib_kernel<<<nb_e, 256, 0, stream>>>(ssrc, srel, hA,   Win2, bin2, Wout2, contrib, E);
    segsum_kernel<<<nb_s, 256, 0, stream>>>(start, counts, contrib, hA,   wself + 256, bout2, hB, n);
    // Layer 3: hB -> hA
    edge_contrib_kernel<<<nb_e, 256, 0, stream>>>(ssrc, srel, hB,   Win3, bin3, Wout3, contrib, E);
    segsum_kernel<<<nb_s, 256, 0, stream>>>(start, counts, contrib, hB,   wself + 512, bout3, hA, n);

    decode_kernel<<<nb_e, 256, 0, stream>>>(ei, hA, Wd1, bd1, Wd2, bd2, Wd3, bd3,
                                            outp, E);
}

// Round 6
// 365.838 us; speedup vs baseline: 9.1625x; 1.0126x over previous
//
#include <hip/hip_runtime.h>
#include <math.h>

// ---------------------------------------------------------------------------
// SpatialGCN:
//  * CSR (dst-grouped, UNORDERED groups) built via hist -> block-scan
//    reservation -> scatter. No serial device scan.
//  * Per layer: edge-parallel contribution kernel (plain stores, no atomics)
//    + node segmented-sum kernel (4 threads/node).
//  * Self-loops + bias folded into segsum via Wself.
//  * R6: hot math rewritten with ext_vector float2 so gfx950 emits packed
//    fp32 (v_pk_fma_f32) — 2 FMA/lane/cycle instead of 1.
// ---------------------------------------------------------------------------

typedef __attribute__((ext_vector_type(2))) float f32x2;

__device__ __forceinline__ f32x2 pkfma(f32x2 a, f32x2 b, f32x2 c) {
    return __builtin_elementwise_fma(a, b, c);
}

struct WPtrs {
    const float* bin0; const float* wout0;
    const float* bin1; const float* wout1;
    const float* bin2; const float* wout2;
};

// Extract packed pos (N x 2) and feat (N x 16) from x (N x 18).
__global__ __launch_bounds__(256) void prep_kernel(
    const float* __restrict__ x, float* __restrict__ pos,
    float* __restrict__ feat, int n)
{
    int i = blockIdx.x * 256 + threadIdx.x;
    if (i >= n) return;
    const float* r = x + (size_t)i * 18;
    float2 p; p.x = r[0]; p.y = r[1];
    ((float2*)pos)[i] = p;
    float4* fp = (float4*)feat + (size_t)i * 4;
    fp[0] = make_float4(r[2],  r[3],  r[4],  r[5]);
    fp[1] = make_float4(r[6],  r[7],  r[8],  r[9]);
    fp[2] = make_float4(r[10], r[11], r[12], r[13]);
    fp[3] = make_float4(r[14], r[15], r[16], r[17]);
}

// zero counts[n] and the global cursor total (ws is 0xAA-poisoned each call)
__global__ __launch_bounds__(256) void zero_kernel(int* __restrict__ p, int* __restrict__ total, int n)
{
    int i = blockIdx.x * 256 + threadIdx.x;
    if (i < n) p[i] = 0;
    if (i == 0) *total = 0;
}

__global__ __launch_bounds__(256) void hist_kernel(
    const int* __restrict__ ei, int* __restrict__ counts, int E)
{
    int e = blockIdx.x * 256 + threadIdx.x;
    if (e < E) atomicAdd(&counts[ei[E + e]], 1);
}

// Parallel slot reservation: per-block LDS inclusive scan of 256 counts,
// one global atomicAdd per block, write start/cursor.
__global__ __launch_bounds__(256) void reserve_kernel(
    const int* __restrict__ counts, int* __restrict__ start,
    int* __restrict__ cursor, int* __restrict__ total, int n)
{
    __shared__ int sdata[256];
    __shared__ int sbase;
    int t = threadIdx.x;
    int i = blockIdx.x * 256 + t;
    int c = (i < n) ? counts[i] : 0;
    sdata[t] = c;
    __syncthreads();
    #pragma unroll
    for (int off = 1; off < 256; off <<= 1) {
        int v = (t >= off) ? sdata[t - off] : 0;
        __syncthreads();
        sdata[t] += v;
        __syncthreads();
    }
    if (t == 255) sbase = atomicAdd(total, sdata[255]);
    __syncthreads();
    if (i < n) {
        int s = sbase + sdata[t] - c;   // block base + exclusive prefix
        start[i]  = s;
        cursor[i] = s;
    }
}

// Scatter edges into dst-grouped order; precompute rel per sorted edge.
__global__ __launch_bounds__(256) void scatter_kernel(
    const int* __restrict__ ei, const float* __restrict__ pos,
    int* __restrict__ cursor, int* __restrict__ ssrc,
    float2* __restrict__ srel, int E)
{
    int e = blockIdx.x * 256 + threadIdx.x;
    if (e >= E) return;
    int s = ei[e];
    int d = ei[E + e];
    int p = atomicAdd(&cursor[d], 1);
    ssrc[p] = s;
    float2 ps = ((const float2*)pos)[s];
    float2 pd = ((const float2*)pos)[d];
    srel[p] = make_float2(ps.x - pd.x, ps.y - pd.y);
}

// Wself[l][c*16+o] = sum_h relu(bin[h*16+c]) * Wout[(h*16+c)*16+o]
__global__ __launch_bounds__(256) void wself_kernel(WPtrs wp, float* __restrict__ wself)
{
    int l = blockIdx.x;
    const float* bin  = (l == 0) ? wp.bin0  : (l == 1) ? wp.bin1  : wp.bin2;
    const float* wout = (l == 0) ? wp.wout0 : (l == 1) ? wp.wout1 : wp.wout2;
    int t = threadIdx.x;          // t = c*16 + o
    int c = t >> 4, o = t & 15;
    float acc = 0.f;
    #pragma unroll
    for (int h = 0; h < 16; ++h) {
        int hc = h * 16 + c;
        acc += fmaxf(bin[hc], 0.f) * wout[hc * 16 + o];
    }
    wself[l * 256 + t] = acc;
}

// One thread per grouped edge slot: contribution = (relu(rel@Win+bin)*xj)@Wout,
// written to contrib[p][0..16) with plain stores. Packed-fp32 inner math.
__global__ __launch_bounds__(256) void edge_contrib_kernel(
    const int* __restrict__ ssrc,   // [E] grouped src
    const float2* __restrict__ srel,// [E] grouped rel
    const float* __restrict__ fin,  // [N,16]
    const float* __restrict__ Win,  // [2,256]
    const float* __restrict__ bin,  // [256]
    const float* __restrict__ Wout, // [256,16]
    float* __restrict__ contrib,    // [E,16]
    int E)
{
    int p = blockIdx.x * 256 + threadIdx.x;
    bool valid = (p < E);
    int pp = valid ? p : 0;
    int s = ssrc[pp];
    float2 r = srel[pp];

    const float4* fp = (const float4*)fin + (size_t)s * 4;
    float4 a = fp[0], b = fp[1], c4 = fp[2], d4 = fp[3];
    f32x2 xj2[8] = { {a.x,a.y}, {a.z,a.w}, {b.x,b.y}, {b.z,b.w},
                     {c4.x,c4.y}, {c4.z,c4.w}, {d4.x,d4.y}, {d4.z,d4.w} };

    f32x2 rxx = { r.x, r.x };
    f32x2 ryy = { r.y, r.y };
    f32x2 zero2 = { 0.f, 0.f };

    f32x2 acc2[8];
    #pragma unroll
    for (int j = 0; j < 8; ++j) acc2[j] = zero2;

    // weights are wave-uniform -> scalar loads; unroll 1 keeps live-range small
    #pragma unroll 1
    for (int h = 0; h < 16; ++h) {
        #pragma unroll
        for (int c2 = 0; c2 < 8; ++c2) {
            int hc = h * 16 + c2 * 2;               // even -> 8B-aligned pairs
            f32x2 w1 = *(const f32x2*)(Win + hc);
            f32x2 w2 = *(const f32x2*)(Win + 256 + hc);
            f32x2 b2 = *(const f32x2*)(bin + hc);
            f32x2 sv = pkfma(rxx, w1, pkfma(ryy, w2, b2));
            sv = __builtin_elementwise_max(sv, zero2);
            f32x2 t = sv * xj2[c2];
            f32x2 t0 = { t.x, t.x };
            f32x2 t1 = { t.y, t.y };
            const f32x2* wr0 = (const f32x2*)(Wout + (size_t)hc * 16);
            const f32x2* wr1 = (const f32x2*)(Wout + (size_t)(hc + 1) * 16);
            #pragma unroll
            for (int j = 0; j < 8; ++j)
                acc2[j] = pkfma(t0, wr0[j], acc2[j]);
            #pragma unroll
            for (int j = 0; j < 8; ++j)
                acc2[j] = pkfma(t1, wr1[j], acc2[j]);
        }
    }

    if (valid) {
        float4* op = (float4*)(contrib + (size_t)p * 16);
        op[0] = make_float4(acc2[0].x, acc2[0].y, acc2[1].x, acc2[1].y);
        op[1] = make_float4(acc2[2].x, acc2[2].y, acc2[3].x, acc2[3].y);
        op[2] = make_float4(acc2[4].x, acc2[4].y, acc2[5].x, acc2[5].y);
        op[3] = make_float4(acc2[6].x, acc2[6].y, acc2[7].x, acc2[7].y);
    }
}

// 4 threads per node, one float4 channel-quad each. Init = bias + self-loop
// (fin[node] @ Wself), then sum grouped contributions over [start, start+cnt).
__global__ __launch_bounds__(256) void segsum_kernel(
    const int* __restrict__ start, const int* __restrict__ counts,
    const float* __restrict__ contrib,
    const float* __restrict__ fin, const float* __restrict__ wself,
    const float* __restrict__ bout, float* __restrict__ out, int n)
{
    int tid = blockIdx.x * 256 + threadIdx.x;
    int node = tid >> 2;
    int q = tid & 3;            // channel quad index
    if (node >= n) return;

    const float4* ip = (const float4*)fin + (size_t)node * 4;
    float4 f0 = ip[0], f1 = ip[1], f2 = ip[2], f3 = ip[3];
    float xin[16] = { f0.x,f0.y,f0.z,f0.w, f1.x,f1.y,f1.z,f1.w,
                      f2.x,f2.y,f2.z,f2.w, f3.x,f3.y,f3.z,f3.w };

    float4 bi = ((const float4*)bout)[q];
    f32x2 accA = { bi.x, bi.y };
    f32x2 accB = { bi.z, bi.w };
    #pragma unroll
    for (int c = 0; c < 16; ++c) {
        f32x2 tt = { xin[c], xin[c] };
        const f32x2* w = (const f32x2*)(wself + c * 16) + q * 2;
        accA = pkfma(tt, w[0], accA);
        accB = pkfma(tt, w[1], accB);
    }

    int b = start[node];
    int e = b + counts[node];
    for (int k = b; k < e; ++k) {
        float4 v = ((const float4*)contrib)[(size_t)k * 4 + q];
        accA.x += v.x; accA.y += v.y;
        accB.x += v.z; accB.y += v.w;
    }

    ((float4*)(out + (size_t)node * 16))[q] =
        make_float4(accA.x, accA.y, accB.x, accB.y);
}

// Edge MLP: sigmoid(relu(relu([h_s,h_d]@Wd1+b1)@Wd2+b2)@Wd3+b3) — packed fp32.
__global__ __launch_bounds__(256) void decode_kernel(
    const int* __restrict__ ei, const float* __restrict__ h,
    const float* __restrict__ Wd1, const float* __restrict__ bd1,
    const float* __restrict__ Wd2, const float* __restrict__ bd2,
    const float* __restrict__ Wd3, const float* __restrict__ bd3,
    float* __restrict__ out, int E)
{
    int tid = blockIdx.x * 256 + threadIdx.x;
    bool valid = (tid < E);
    int e = valid ? tid : 0;
    int s = ei[e];
    int d = ei[E + e];

    const float4* hp = (const float4*)h + (size_t)s * 4;
    float4 a = hp[0], b = hp[1], c4 = hp[2], d4 = hp[3];
    float hs[16] = { a.x,a.y,a.z,a.w, b.x,b.y,b.z,b.w,
                     c4.x,c4.y,c4.z,c4.w, d4.x,d4.y,d4.z,d4.w };
    const float4* hq = (const float4*)h + (size_t)d * 4;
    float4 e0 = hq[0], e1 = hq[1], e2 = hq[2], e3 = hq[3];
    float hd[16] = { e0.x,e0.y,e0.z,e0.w, e1.x,e1.y,e1.z,e1.w,
                     e2.x,e2.y,e2.z,e2.w, e3.x,e3.y,e3.z,e3.w };

    f32x2 zero2 = { 0.f, 0.f };

    f32x2 z1[8];
    #pragma unroll
    for (int j = 0; j < 8; ++j) z1[j] = *((const f32x2*)bd1 + j);
    #pragma unroll
    for (int c = 0; c < 16; ++c) {
        f32x2 uu = { hs[c], hs[c] };
        f32x2 vv = { hd[c], hd[c] };
        const f32x2* wu = (const f32x2*)(Wd1 + (size_t)c * 16);
        const f32x2* wv = (const f32x2*)(Wd1 + (size_t)(16 + c) * 16);
        #pragma unroll
        for (int j = 0; j < 8; ++j)
            z1[j] = pkfma(uu, wu[j], pkfma(vv, wv[j], z1[j]));
    }
    #pragma unroll
    for (int j = 0; j < 8; ++j) z1[j] = __builtin_elementwise_max(z1[j], zero2);

    f32x2 z2[8];
    #pragma unroll
    for (int j = 0; j < 8; ++j) z2[j] = *((const f32x2*)bd2 + j);
    #pragma unroll
    for (int c = 0; c < 16; ++c) {
        float tc = z1[c >> 1][c & 1];
        f32x2 tt = { tc, tc };
        const f32x2* w = (const f32x2*)(Wd2 + (size_t)c * 16);
        #pragma unroll
        for (int j = 0; j < 8; ++j)
            z2[j] = pkfma(tt, w[j], z2[j]);
    }
    #pragma unroll
    for (int j = 0; j < 8; ++j) z2[j] = __builtin_elementwise_max(z2[j], zero2);

    f32x2 y2 = zero2;
    #pragma unroll
    for (int j = 0; j < 8; ++j)
        y2 = pkfma(z2[j], *((const f32x2*)Wd3 + j), y2);
    float y = y2.x + y2.y + bd3[0];

    if (valid)
        out[tid] = 1.f / (1.f + expf(-y));
}

extern "C" void kernel_launch(void* const* d_in, const int* in_sizes, int n_in,
                              void* d_out, int out_size, void* d_ws, size_t ws_size,
                              hipStream_t stream)
{
    const float* x     = (const float*)d_in[0];
    const int*   ei    = (const int*)  d_in[1];
    const float* Win1  = (const float*)d_in[2];
    const float* bin1  = (const float*)d_in[3];
    const float* Wout1 = (const float*)d_in[4];
    const float* bout1 = (const float*)d_in[5];
    const float* Win2  = (const float*)d_in[6];
    const float* bin2  = (const float*)d_in[7];
    const float* Wout2 = (const float*)d_in[8];
    const float* bout2 = (const float*)d_in[9];
    const float* Win3  = (const float*)d_in[10];
    const float* bin3  = (const float*)d_in[11];
    const float* Wout3 = (const float*)d_in[12];
    const float* bout3 = (const float*)d_in[13];
    const float* Wd1   = (const float*)d_in[14];
    const float* bd1   = (const float*)d_in[15];
    const float* Wd2   = (const float*)d_in[16];
    const float* bd2   = (const float*)d_in[17];
    const float* Wd3   = (const float*)d_in[18];
    const float* bd3   = (const float*)d_in[19];

    int n = in_sizes[0] / 18;
    int E = in_sizes[1] / 2;

    float* ws      = (float*)d_ws;
    float* pos     = ws;                        // 2n
    float* feat    = pos   + (size_t)2 * n;     // 16n
    float* hA      = feat  + (size_t)16 * n;    // 16n
    float* hB      = hA    + (size_t)16 * n;    // 16n
    float* wself   = hB    + (size_t)16 * n;    // 768
    int* counts    = (int*)(wself + 768);       // n
    int* start     = counts + n;                // n
    int* cursor    = start + n;                 // n
    int* total     = cursor + n;                // 1 (+1 pad -> 8B align)
    int* ssrc      = total + 2;                 // E
    float2* srel   = (float2*)(ssrc + E);       // E (8B aligned)
    float* contrib = (float*)(srel + E);        // 16E (32 MB, reused per layer)
    float* outp    = (float*)d_out;

    int nb_n  = (n + 255) / 256;
    int nb_e  = (E + 255) / 256;
    int nb_s  = (4 * n + 255) / 256;

    prep_kernel<<<nb_n, 256, 0, stream>>>(x, pos, feat, n);
    zero_kernel<<<nb_n, 256, 0, stream>>>(counts, total, n);
    hist_kernel<<<nb_e, 256, 0, stream>>>(ei, counts, E);
    reserve_kernel<<<nb_n, 256, 0, stream>>>(counts, start, cursor, total, n);
    scatter_kernel<<<nb_e, 256, 0, stream>>>(ei, pos, cursor, ssrc, srel, E);

    WPtrs wp { bin1, Wout1, bin2, Wout2, bin3, Wout3 };
    wself_kernel<<<3, 256, 0, stream>>>(wp, wself);

    // Layer 1: feat -> hA
    edge_contrib_kernel<<<nb_e, 256, 0, stream>>>(ssrc, srel, feat, Win1, bin1, Wout1, contrib, E);
    segsum_kernel<<<nb_s, 256, 0, stream>>>(start, counts, contrib, feat, wself + 0,   bout1, hA, n);
    // Layer 2: hA -> hB
    edge_contrib_kernel<<<nb_e, 256, 0, stream>>>(ssrc, srel, hA,   Win2, bin2, Wout2, contrib, E);
    segsum_kernel<<<nb_s, 256, 0, stream>>>(start, counts, contrib, hA,   wself + 256, bout2, hB, n);
    // Layer 3: hB -> hA
    edge_contrib_kernel<<<nb_e, 256, 0, stream>>>(ssrc, srel, hB,   Win3, bin3, Wout3, contrib, E);
    segsum_kernel<<<nb_s, 256, 0, stream>>>(start, counts, contrib, hB,   wself + 512, bout3, hA, n);

    decode_kernel<<<nb_e, 256, 0, stream>>>(ei, hA, Wd1, bd1, Wd2, bd2, Wd3, bd3,
                                            outp, E);
}